// Round 9
// baseline (40.630 us; speedup 1.0000x reference)
//
#include <hip/hip_runtime.h>
#include <math.h>

#define NUM_CLASSES 80
#define OBJ_BLOCKS 1536                 // 3 scales x 16 batch x 32 targets
#define NEG0_BLOCKS 150                 // 76800 float4 / 512 (exact)
#define NEG1_BLOCKS 38                  // ceil(19200 / 512)
#define NEG2_BLOCKS 10                  // ceil(4800 / 512)
#define NEG_BLOCKS (NEG0_BLOCKS + NEG1_BLOCKS + NEG2_BLOCKS)   // 198
#define TOTAL_BLOCKS (OBJ_BLOCKS + NEG_BLOCKS + 1)             // 1735
#define NEG_BASE (OBJ_BLOCKS * 8)       // float offset of neg partials in ws

// ---- math helpers (match jax.nn.log_sigmoid / sigmoid in f32) ----
__device__ __forceinline__ float softplusf_(float x) {
    return x > 0.f ? x + log1pf(expf(-x)) : log1pf(expf(x));
}
__device__ __forceinline__ float sigmoidf_(float x) {
    return 1.f / (1.f + expf(-x));
}
// focal_bce(x, t=0) = softplus(x) * sigmoid(x)^2   (strictly > 0 for finite x)
__device__ __forceinline__ float focal0(float x) {
    float s = sigmoidf_(x);
    return softplusf_(x) * s * s;
}
// focal_bce(x, t=1) = softplus(-x) * sigmoid(-x)^2
__device__ __forceinline__ float focal1(float x) {
    float s = sigmoidf_(-x);
    return softplusf_(-x) * s * s;
}

// agent-scope ws accessors: stores/loads go to the die-level LLC (shared
// across the 8 non-coherent per-XCD L2s) -> producer/consumer safe.
__device__ __forceinline__ void st_ws(float* p, float v) {
    __hip_atomic_store(p, v, __ATOMIC_RELAXED, __HIP_MEMORY_SCOPE_AGENT);
}
__device__ __forceinline__ void st_ws_rel(float* p, float v) {
    __hip_atomic_store(p, v, __ATOMIC_RELEASE, __HIP_MEMORY_SCOPE_AGENT);
}
__device__ __forceinline__ float ld_ws(const float* p) {
    return __hip_atomic_load(p, __ATOMIC_RELAXED, __HIP_MEMORY_SCOPE_AGENT);
}

// ws layout (floats), total 1536*8 + 198 = 12486 floats (< R8's 52 KB use):
//   [bid*8 .. +5]   obj data: [0]=xy [1]=wh [2]=cls [3]=pos [4]=neg_corr [5]=count
//   [bid*8 + 6]     obj flag: 1.0f when written (reset to -1.0f by finalizer)
//   [NEG_BASE + q]  neg partial (strictly > 0 when written; reset to -1.0f)
// Completion protocol: DISTINCT flag word per block (no single-line RMW --
// R7's one-counter fetch_add serialized at ~73ns x 2324 = 170us). Initial
// memory is 0x00.. or 0xAA.. poison -> fails both ==1.0f and >0.0f tests;
// finalizer resets flags to -1.0f each call -> deterministic across replays.

template<int NI, int PLANE4>
__device__ __forceinline__ float neg_sum(const float* __restrict__ P,
                                         int lq, int f) {
    float sum = 0.f;
    #pragma unroll
    for (int k = 0; k < 4; ++k) {
        const int idx = lq * 512 + k * 128 + f;
        if (idx < NI) {
            const int plane = idx / PLANE4;          // compile-time divisor
            const int r4 = idx - plane * PLANE4;
            const int b = plane / 3;
            const int a = plane - b * 3;
            const float4 v = *reinterpret_cast<const float4*>(
                P + (size_t)(b * 255 + a * 85 + 4) * (PLANE4 * 4)
                  + (size_t)r4 * 4);
            sum += focal0(v.x) + focal0(v.y) + focal0(v.z) + focal0(v.w);
        }
    }
    return sum;
}

__global__ __launch_bounds__(128)
void fused_kernel(const float* __restrict__ p0,
                  const float* __restrict__ p1,
                  const float* __restrict__ p2,
                  const float* __restrict__ tgt,
                  float* __restrict__ ws,
                  float* __restrict__ out) {
    __shared__ int   s_cell[32];
    __shared__ int   s_cls[32];
    __shared__ float s_sum[5];
    __shared__ float s_ns[2];
    __shared__ float s_red[2][6];
    __shared__ float s_nred[2][3];

    const int bid = blockIdx.x;
    const int f   = threadIdx.x;          // 128 threads = 2 waves

    if (bid < OBJ_BLOCKS) {
        // ================= object-cell path =================
        const int s = bid >> 9;            // /512
        const int r = bid & 511;
        const int b = r >> 5;              // /32
        const int t = r & 31;
        const int H  = (s == 0) ? 80 : (s == 1 ? 40 : 20);
        const int W  = H;
        const int HW = H * W;

        float aw0, aw1, aw2, ah0, ah1, ah2;
        if (s == 0) { aw0=10.f/640.f; aw1=16.f/640.f; aw2=33.f/640.f;
                      ah0=13.f/640.f; ah1=30.f/640.f; ah2=23.f/640.f; }
        else if (s == 1) { aw0=30.f/640.f; aw1=62.f/640.f; aw2=59.f/640.f;
                           ah0=61.f/640.f; ah1=45.f/640.f; ah2=119.f/640.f; }
        else { aw0=116.f/640.f; aw1=156.f/640.f; aw2=373.f/640.f;
               ah0=90.f/640.f;  ah1=198.f/640.f; ah2=326.f/640.f; }

        if (f < 5) s_sum[f] = 0.f;

        if (f < 32) {
            const float* tg = tgt + (size_t)(b * 32 + f) * 5;
            const float w = tg[3], h = tg[4];
            int cell = -1;
            if (w > 0.f && h > 0.f) {
                // argmax IoU over 3 anchors, first-max on ties (strict >)
                float best = -1.f; int ba = 0;
                float inter = fminf(w, aw0) * fminf(h, ah0);
                float iou = inter / (w * h + aw0 * ah0 - inter + 1e-6f);
                if (iou > best) { best = iou; ba = 0; }
                inter = fminf(w, aw1) * fminf(h, ah1);
                iou = inter / (w * h + aw1 * ah1 - inter + 1e-6f);
                if (iou > best) { best = iou; ba = 1; }
                inter = fminf(w, aw2) * fminf(h, ah2);
                iou = inter / (w * h + aw2 * ah2 - inter + 1e-6f);
                if (iou > best) { best = iou; ba = 2; }
                const float xw = tg[1] * (float)W, yh = tg[2] * (float)H;
                int gi = (int)xw; gi = min(max(gi, 0), W - 1); // trunc == astype(i32)
                int gj = (int)yh; gj = min(max(gj, 0), H - 1);
                cell = (ba * H + gj) * W + gi;                 // b uniform in block
            }
            s_cell[f] = cell;
            s_cls[f]  = (int)tg[0];
        }
        __syncthreads();

        const int mycell = s_cell[t];
        bool winner = (mycell >= 0);
        if (winner) {
            // numpy scatter = last-write-wins in t order within the batch
            #pragma unroll 1
            for (int t2 = t + 1; t2 < 32; ++t2)
                if (s_cell[t2] == mycell) { winner = false; break; }
        }
        // `winner` is block-uniform (depends only on bid)

        if (winner) {
            // class UNION over all targets hitting this cell
            unsigned um0 = 0, um1 = 0, um2 = 0;
            #pragma unroll 1
            for (int t2 = 0; t2 < 32; ++t2) {
                if (s_cell[t2] == mycell) {
                    const int c = s_cls[t2];
                    if (c < 32)      um0 |= 1u << c;
                    else if (c < 64) um1 |= 1u << (c - 32);
                    else             um2 |= 1u << (c - 64);
                }
            }

            // geometry of target t (uniform; recomputed by all lanes)
            const float* tg = tgt + (size_t)(b * 32 + t) * 5;
            const float w = tg[3], h = tg[4];
            float best = -1.f; int ba = 0;
            {
                float inter = fminf(w, aw0) * fminf(h, ah0);
                float iou = inter / (w * h + aw0 * ah0 - inter + 1e-6f);
                if (iou > best) { best = iou; ba = 0; }
                inter = fminf(w, aw1) * fminf(h, ah1);
                iou = inter / (w * h + aw1 * ah1 - inter + 1e-6f);
                if (iou > best) { best = iou; ba = 1; }
                inter = fminf(w, aw2) * fminf(h, ah2);
                iou = inter / (w * h + aw2 * ah2 - inter + 1e-6f);
                if (iou > best) { best = iou; ba = 2; }
            }
            const float aw = (ba == 0) ? aw0 : (ba == 1 ? aw1 : aw2);
            const float ah = (ba == 0) ? ah0 : (ba == 1 ? ah1 : ah2);
            const float xw = tg[1] * (float)W, yh = tg[2] * (float)H;
            int gi = (int)xw; gi = min(max(gi, 0), W - 1);
            int gj = (int)yh; gj = min(max(gj, 0), H - 1);

            if (f < 85) {
                const float* P = (s == 0) ? p0 : (s == 1 ? p1 : p2);
                const float val = P[(size_t)(b * 255 + ba * 85 + f) * HW
                                    + (size_t)gj * W + gi];
                float contrib; int cat;
                if (f == 0) {
                    const float d = sigmoidf_(val) - (xw - (float)gi);
                    contrib = d * d; cat = 0;
                } else if (f == 1) {
                    const float d = sigmoidf_(val) - (yh - (float)gj);
                    contrib = d * d; cat = 0;
                } else if (f == 2) {
                    const float e = val - logf(w / aw + 1e-6f);
                    contrib = e * e; cat = 1;
                } else if (f == 3) {
                    const float e = val - logf(h / ah + 1e-6f);
                    contrib = e * e; cat = 1;
                } else if (f == 4) {
                    contrib = focal1(val); cat = 3;
                    atomicAdd(&s_sum[4], -focal0(val)); // correction to all-cell neg
                } else {
                    const int c = f - 5;
                    const bool ts = (c < 32) ? ((um0 >> c) & 1)
                                  : (c < 64) ? ((um1 >> (c - 32)) & 1)
                                             : ((um2 >> (c - 64)) & 1);
                    contrib = ts ? focal1(val) : focal0(val); cat = 2;
                }
                atomicAdd(&s_sum[cat], contrib);
            }
        }
        __syncthreads();
        // thread 0 issues ALL data stores, then the release flag: release by
        // the same thread orders its prior agent stores at the LLC.
        if (f == 0) {
            float* slot = ws + (size_t)bid * 8;
            #pragma unroll
            for (int k = 0; k < 5; ++k)
                st_ws(slot + k, winner ? s_sum[k] : 0.f);
            st_ws(slot + 5, winner ? 1.f : 0.f);     // count
            st_ws_rel(slot + 6, 1.0f);               // flag
        }
    } else if (bid < OBJ_BLOCKS + NEG_BLOCKS) {
        // ================= all-cell negative path =================
        const int q = bid - OBJ_BLOCKS;    // 0..197
        float sum;
        if (q < NEG0_BLOCKS)
            sum = neg_sum<76800, 1600>(p0, q, f);
        else if (q < NEG0_BLOCKS + NEG1_BLOCKS)
            sum = neg_sum<19200, 400>(p1, q - NEG0_BLOCKS, f);
        else
            sum = neg_sum<4800, 100>(p2, q - NEG0_BLOCKS - NEG1_BLOCKS, f);
        #pragma unroll
        for (int off = 32; off; off >>= 1) sum += __shfl_down(sum, off, 64);
        if ((f & 63) == 0) s_ns[f >> 6] = sum;
        __syncthreads();
        // partial is strictly positive -> it IS the flag (>0 test)
        if (f == 0) st_ws_rel(ws + NEG_BASE + q, s_ns[0] + s_ns[1]);
    } else {
        // ================= finalizer block (spins, reduces) =================
        // Co-residency guaranteed: 1735 blocks x 2 waves = 3470 waves <= 4096
        // blocks/CU capacity at 128 thr -> spin cannot deadlock.
        const int lane = f & 63;
        const int wid  = f >> 6;

        // Phase A: wait for all producer flags (relaxed agent loads, L1-bypass)
        for (int i = f; i < OBJ_BLOCKS; i += 128) {
            const float* fp = ws + (size_t)i * 8 + 6;
            while (ld_ws(fp) != 1.0f) __builtin_amdgcn_s_sleep(2);
        }
        for (int q = f; q < NEG_BLOCKS; q += 128) {
            const float* np = ws + NEG_BASE + q;
            while (!(ld_ws(np) > 0.0f)) __builtin_amdgcn_s_sleep(2);
        }
        __syncthreads();
        __threadfence();   // acquire side, once

        // neg partials -> per-scale sums
        float n0 = 0.f, n1 = 0.f, n2 = 0.f;
        for (int q = f; q < NEG_BLOCKS; q += 128) {
            const float v = ld_ws(ws + NEG_BASE + q);
            if (q < NEG0_BLOCKS)                    n0 += v;
            else if (q < NEG0_BLOCKS + NEG1_BLOCKS) n1 += v;
            else                                    n2 += v;
        }
        #pragma unroll
        for (int off = 32; off; off >>= 1) {
            n0 += __shfl_down(n0, off, 64);
            n1 += __shfl_down(n1, off, 64);
            n2 += __shfl_down(n2, off, 64);
        }
        if (lane == 0) { s_nred[wid][0] = n0; s_nred[wid][1] = n1; s_nred[wid][2] = n2; }

        float total = 0.f;                  // live in thread 0
        #pragma unroll 1
        for (int s = 0; s < 3; ++s) {
            float v[6] = {0.f, 0.f, 0.f, 0.f, 0.f, 0.f};
            for (int i = f; i < 512; i += 128) {    // 4 slots per thread
                const float* sl = ws + (size_t)(s * 512 + i) * 8;
                #pragma unroll
                for (int k = 0; k < 6; ++k) v[k] += ld_ws(sl + k);
            }
            #pragma unroll
            for (int off = 32; off; off >>= 1)
                #pragma unroll
                for (int k = 0; k < 6; ++k) v[k] += __shfl_down(v[k], off, 64);
            if (lane == 0) {
                #pragma unroll
                for (int k = 0; k < 6; ++k) s_red[wid][k] = v[k];
            }
            __syncthreads();
            if (f == 0) {
                const float sxy  = s_red[0][0] + s_red[1][0];
                const float swh  = s_red[0][1] + s_red[1][1];
                const float scls = s_red[0][2] + s_red[1][2];
                const float spos = s_red[0][3] + s_red[1][3];
                const float scor = s_red[0][4] + s_red[1][4];
                const float nobj = s_red[0][5] + s_red[1][5];
                const float negs = s_nred[0][s] + s_nred[1][s];
                const float Ns = (s == 0) ? (float)(16 * 3 * 6400)
                               : (s == 1) ? (float)(16 * 3 * 1600)
                                          : (float)(16 * 3 * 400);
                const float n_noobj = Ns - nobj;
                const float lxywh = (sxy + swh) / fmaxf(2.f * nobj, 1.f);
                const float lcls  = scls / fmaxf(nobj * (float)NUM_CLASSES, 1.f);
                const float lpos  = spos / fmaxf(nobj, 1.f);
                const float lneg  = (negs + scor) / fmaxf(n_noobj, 1.f);
                const float has   = (nobj > 0.f) ? 1.f : 0.f;
                total += 5.f * lxywh * has + lpos * has + 0.5f * lneg + lcls * has;
            }
            __syncthreads();
        }
        if (f == 0) out[0] = total / 3.f;

        // reset flags for the next call (kernel-end completion makes these
        // visible before any subsequent launch can run)
        __syncthreads();
        for (int i = f; i < OBJ_BLOCKS; i += 128)
            st_ws(ws + (size_t)i * 8 + 6, -1.0f);
        for (int q = f; q < NEG_BLOCKS; q += 128)
            st_ws(ws + NEG_BASE + q, -1.0f);
    }
}

extern "C" void kernel_launch(void* const* d_in, const int* in_sizes, int n_in,
                              void* d_out, int out_size, void* d_ws, size_t ws_size,
                              hipStream_t stream) {
    const float* p0  = (const float*)d_in[0];
    const float* p1  = (const float*)d_in[1];
    const float* p2  = (const float*)d_in[2];
    const float* tgt = (const float*)d_in[3];
    float* ws  = (float*)d_ws;   // uses 12486 floats ~= 49 KB
    float* out = (float*)d_out;

    fused_kernel<<<TOTAL_BLOCKS, 128, 0, stream>>>(p0, p1, p2, tgt, ws, out);
}

// Round 10
// 31.771 us; speedup vs baseline: 1.2788x; 1.2788x over previous
//
#include <hip/hip_runtime.h>
#include <math.h>

#define NUM_CLASSES 80
#define OBJ_BLOCKS 1536                 // 3 scales x 16 batch x 32 targets
#define NEG0_BLOCKS 150                 // 76800 float4 / 512 (exact)
#define NEG1_BLOCKS 38                  // ceil(19200 / 512)
#define NEG2_BLOCKS 10                  // ceil(4800 / 512)
#define NEG_BLOCKS (NEG0_BLOCKS + NEG1_BLOCKS + NEG2_BLOCKS)   // 198
#define TOTAL_BLOCKS (OBJ_BLOCKS + NEG_BLOCKS + 1)             // 1735
#define NEG_BASE (OBJ_BLOCKS * 8)       // float offset of neg partials in ws

// ---- math helpers (match jax.nn.log_sigmoid / sigmoid in f32) ----
__device__ __forceinline__ float softplusf_(float x) {
    return x > 0.f ? x + log1pf(expf(-x)) : log1pf(expf(x));
}
__device__ __forceinline__ float sigmoidf_(float x) {
    return 1.f / (1.f + expf(-x));
}
// focal_bce(x, t=0) = softplus(x) * sigmoid(x)^2   (strictly > 0 for |x|<87)
__device__ __forceinline__ float focal0(float x) {
    float s = sigmoidf_(x);
    return softplusf_(x) * s * s;
}
// focal_bce(x, t=1) = softplus(-x) * sigmoid(-x)^2
__device__ __forceinline__ float focal1(float x) {
    float s = sigmoidf_(-x);
    return softplusf_(-x) * s * s;
}

// agent-scope RELAXED atomics: compile to sc1-flagged global ops that are
// individually coherent at the die-level LLC (cross-XCD safe). NO release/
// acquire anywhere: R9 showed agent-release emits an L2-writeback per block
// (1734x => +25us). Ordering data-before-flag is done with an explicit
// `s_waitcnt vmcnt(0)` in the producing wave (waits only its own stores).
__device__ __forceinline__ void st_ws(float* p, float v) {
    __hip_atomic_store(p, v, __ATOMIC_RELAXED, __HIP_MEMORY_SCOPE_AGENT);
}
__device__ __forceinline__ float ld_ws(const float* p) {
    return __hip_atomic_load(p, __ATOMIC_RELAXED, __HIP_MEMORY_SCOPE_AGENT);
}

// ws layout (floats), total 1536*8 + 198 = 12486 floats:
//   [bid*8 .. +5]   obj data: [0]=xy [1]=wh [2]=cls [3]=pos [4]=neg_corr [5]=count
//   [bid*8 + 6]     obj flag: 1.0f when written (reset to -1.0f by finalizer)
//   [NEG_BASE + q]  neg partial; strictly > 0 when written => self-flagging
// First call: ws holds 0x00/0xAA poison; both fail the ==1.0f / >0.0f tests.
// Finalizer resets all flags to -1.0f each call => replay-deterministic.

template<int NI, int PLANE4>
__device__ __forceinline__ float neg_sum(const float* __restrict__ P,
                                         int lq, int f) {
    float sum = 0.f;
    #pragma unroll
    for (int k = 0; k < 4; ++k) {
        const int idx = lq * 512 + k * 128 + f;
        if (idx < NI) {
            const int plane = idx / PLANE4;          // compile-time divisor
            const int r4 = idx - plane * PLANE4;
            const int b = plane / 3;
            const int a = plane - b * 3;
            const float4 v = *reinterpret_cast<const float4*>(
                P + (size_t)(b * 255 + a * 85 + 4) * (PLANE4 * 4)
                  + (size_t)r4 * 4);
            sum += focal0(v.x) + focal0(v.y) + focal0(v.z) + focal0(v.w);
        }
    }
    return sum;
}

__global__ __launch_bounds__(128)
void fused_kernel(const float* __restrict__ p0,
                  const float* __restrict__ p1,
                  const float* __restrict__ p2,
                  const float* __restrict__ tgt,
                  float* __restrict__ ws,
                  float* __restrict__ out) {
    __shared__ int   s_cell[32];
    __shared__ int   s_cls[32];
    __shared__ float s_sum[5];
    __shared__ float s_ns[2];
    __shared__ float s_red[2][6];
    __shared__ float s_nred[2][3];

    const int bid = blockIdx.x;
    const int f   = threadIdx.x;          // 128 threads = 2 waves

    if (bid < OBJ_BLOCKS) {
        // ================= object-cell path =================
        const int s = bid >> 9;            // /512
        const int r = bid & 511;
        const int b = r >> 5;              // /32
        const int t = r & 31;
        const int H  = (s == 0) ? 80 : (s == 1 ? 40 : 20);
        const int W  = H;
        const int HW = H * W;

        float aw0, aw1, aw2, ah0, ah1, ah2;
        if (s == 0) { aw0=10.f/640.f; aw1=16.f/640.f; aw2=33.f/640.f;
                      ah0=13.f/640.f; ah1=30.f/640.f; ah2=23.f/640.f; }
        else if (s == 1) { aw0=30.f/640.f; aw1=62.f/640.f; aw2=59.f/640.f;
                           ah0=61.f/640.f; ah1=45.f/640.f; ah2=119.f/640.f; }
        else { aw0=116.f/640.f; aw1=156.f/640.f; aw2=373.f/640.f;
               ah0=90.f/640.f;  ah1=198.f/640.f; ah2=326.f/640.f; }

        if (f < 5) s_sum[f] = 0.f;

        if (f < 32) {
            const float* tg = tgt + (size_t)(b * 32 + f) * 5;
            const float w = tg[3], h = tg[4];
            int cell = -1;
            if (w > 0.f && h > 0.f) {
                // argmax IoU over 3 anchors, first-max on ties (strict >)
                float best = -1.f; int ba = 0;
                float inter = fminf(w, aw0) * fminf(h, ah0);
                float iou = inter / (w * h + aw0 * ah0 - inter + 1e-6f);
                if (iou > best) { best = iou; ba = 0; }
                inter = fminf(w, aw1) * fminf(h, ah1);
                iou = inter / (w * h + aw1 * ah1 - inter + 1e-6f);
                if (iou > best) { best = iou; ba = 1; }
                inter = fminf(w, aw2) * fminf(h, ah2);
                iou = inter / (w * h + aw2 * ah2 - inter + 1e-6f);
                if (iou > best) { best = iou; ba = 2; }
                const float xw = tg[1] * (float)W, yh = tg[2] * (float)H;
                int gi = (int)xw; gi = min(max(gi, 0), W - 1); // trunc == astype(i32)
                int gj = (int)yh; gj = min(max(gj, 0), H - 1);
                cell = (ba * H + gj) * W + gi;                 // b uniform in block
            }
            s_cell[f] = cell;
            s_cls[f]  = (int)tg[0];
        }
        __syncthreads();

        const int mycell = s_cell[t];
        bool winner = (mycell >= 0);
        if (winner) {
            // numpy scatter = last-write-wins in t order within the batch
            #pragma unroll 1
            for (int t2 = t + 1; t2 < 32; ++t2)
                if (s_cell[t2] == mycell) { winner = false; break; }
        }
        // `winner` is block-uniform (depends only on bid)

        if (winner) {
            // class UNION over all targets hitting this cell
            unsigned um0 = 0, um1 = 0, um2 = 0;
            #pragma unroll 1
            for (int t2 = 0; t2 < 32; ++t2) {
                if (s_cell[t2] == mycell) {
                    const int c = s_cls[t2];
                    if (c < 32)      um0 |= 1u << c;
                    else if (c < 64) um1 |= 1u << (c - 32);
                    else             um2 |= 1u << (c - 64);
                }
            }

            // geometry of target t (uniform; recomputed by all lanes)
            const float* tg = tgt + (size_t)(b * 32 + t) * 5;
            const float w = tg[3], h = tg[4];
            float best = -1.f; int ba = 0;
            {
                float inter = fminf(w, aw0) * fminf(h, ah0);
                float iou = inter / (w * h + aw0 * ah0 - inter + 1e-6f);
                if (iou > best) { best = iou; ba = 0; }
                inter = fminf(w, aw1) * fminf(h, ah1);
                iou = inter / (w * h + aw1 * ah1 - inter + 1e-6f);
                if (iou > best) { best = iou; ba = 1; }
                inter = fminf(w, aw2) * fminf(h, ah2);
                iou = inter / (w * h + aw2 * ah2 - inter + 1e-6f);
                if (iou > best) { best = iou; ba = 2; }
            }
            const float aw = (ba == 0) ? aw0 : (ba == 1 ? aw1 : aw2);
            const float ah = (ba == 0) ? ah0 : (ba == 1 ? ah1 : ah2);
            const float xw = tg[1] * (float)W, yh = tg[2] * (float)H;
            int gi = (int)xw; gi = min(max(gi, 0), W - 1);
            int gj = (int)yh; gj = min(max(gj, 0), H - 1);

            if (f < 85) {
                const float* P = (s == 0) ? p0 : (s == 1 ? p1 : p2);
                const float val = P[(size_t)(b * 255 + ba * 85 + f) * HW
                                    + (size_t)gj * W + gi];
                float contrib; int cat;
                if (f == 0) {
                    const float d = sigmoidf_(val) - (xw - (float)gi);
                    contrib = d * d; cat = 0;
                } else if (f == 1) {
                    const float d = sigmoidf_(val) - (yh - (float)gj);
                    contrib = d * d; cat = 0;
                } else if (f == 2) {
                    const float e = val - logf(w / aw + 1e-6f);
                    contrib = e * e; cat = 1;
                } else if (f == 3) {
                    const float e = val - logf(h / ah + 1e-6f);
                    contrib = e * e; cat = 1;
                } else if (f == 4) {
                    contrib = focal1(val); cat = 3;
                    atomicAdd(&s_sum[4], -focal0(val)); // correction to all-cell neg
                } else {
                    const int c = f - 5;
                    const bool ts = (c < 32) ? ((um0 >> c) & 1)
                                  : (c < 64) ? ((um1 >> (c - 32)) & 1)
                                             : ((um2 >> (c - 64)) & 1);
                    contrib = ts ? focal1(val) : focal0(val); cat = 2;
                }
                atomicAdd(&s_sum[cat], contrib);
            }
        }
        __syncthreads();
        // thread 0: data stores (agent, LLC-coherent) -> drain own stores
        // (vmcnt only; no L2 writeback) -> flag store.
        if (f == 0) {
            float* slot = ws + (size_t)bid * 8;
            #pragma unroll
            for (int k = 0; k < 5; ++k)
                st_ws(slot + k, winner ? s_sum[k] : 0.f);
            st_ws(slot + 5, winner ? 1.f : 0.f);     // count
            asm volatile("s_waitcnt vmcnt(0)" ::: "memory");
            st_ws(slot + 6, 1.0f);                   // flag
        }
    } else if (bid < OBJ_BLOCKS + NEG_BLOCKS) {
        // ================= all-cell negative path =================
        const int q = bid - OBJ_BLOCKS;    // 0..197
        float sum;
        if (q < NEG0_BLOCKS)
            sum = neg_sum<76800, 1600>(p0, q, f);
        else if (q < NEG0_BLOCKS + NEG1_BLOCKS)
            sum = neg_sum<19200, 400>(p1, q - NEG0_BLOCKS, f);
        else
            sum = neg_sum<4800, 100>(p2, q - NEG0_BLOCKS - NEG1_BLOCKS, f);
        #pragma unroll
        for (int off = 32; off; off >>= 1) sum += __shfl_down(sum, off, 64);
        if ((f & 63) == 0) s_ns[f >> 6] = sum;
        __syncthreads();
        // single word, strictly positive -> value IS the flag; no ordering needed
        if (f == 0) st_ws(ws + NEG_BASE + q, s_ns[0] + s_ns[1]);
    } else {
        // ================= finalizer block (spins, reduces) =================
        // Producers never wait on anyone -> no circular wait; co-residency
        // (1735 blocks x 2 waves = 3470 <= 4096 capacity) is a bonus, not a
        // requirement.
        const int lane = f & 63;
        const int wid  = f >> 6;

        // Phase A: vectored spin — all 14 per-thread flags polled per sweep
        // (independent loads -> one LLC-latency round per sweep, not 14).
        {
            const int nq0 = f;                       // neg flag 1 (f < 198 always true for f<128)
            const int nq1 = f + 128;                 // neg flag 2 (valid if < 198)
            for (;;) {
                float v[12];
                #pragma unroll
                for (int k = 0; k < 12; ++k)
                    v[k] = ld_ws(ws + (size_t)(f + 128 * k) * 8 + 6);
                float n0 = ld_ws(ws + NEG_BASE + nq0);
                float n1 = (nq1 < NEG_BLOCKS) ? ld_ws(ws + NEG_BASE + nq1) : 1.f;
                bool ok = (n0 > 0.f) && (n1 > 0.f);
                #pragma unroll
                for (int k = 0; k < 12; ++k) ok &= (v[k] == 1.0f);
                if (ok) break;
                __builtin_amdgcn_s_sleep(1);
            }
        }
        __syncthreads();

        // neg partials -> per-scale sums
        float n0 = 0.f, n1 = 0.f, n2 = 0.f;
        for (int q = f; q < NEG_BLOCKS; q += 128) {
            const float v = ld_ws(ws + NEG_BASE + q);
            if (q < NEG0_BLOCKS)                    n0 += v;
            else if (q < NEG0_BLOCKS + NEG1_BLOCKS) n1 += v;
            else                                    n2 += v;
        }
        #pragma unroll
        for (int off = 32; off; off >>= 1) {
            n0 += __shfl_down(n0, off, 64);
            n1 += __shfl_down(n1, off, 64);
            n2 += __shfl_down(n2, off, 64);
        }
        if (lane == 0) { s_nred[wid][0] = n0; s_nred[wid][1] = n1; s_nred[wid][2] = n2; }

        float total = 0.f;                  // live in thread 0
        #pragma unroll 1
        for (int s = 0; s < 3; ++s) {
            float v[6] = {0.f, 0.f, 0.f, 0.f, 0.f, 0.f};
            for (int i = f; i < 512; i += 128) {    // 4 slots per thread
                const float* sl = ws + (size_t)(s * 512 + i) * 8;
                #pragma unroll
                for (int k = 0; k < 6; ++k) v[k] += ld_ws(sl + k);
            }
            #pragma unroll
            for (int off = 32; off; off >>= 1)
                #pragma unroll
                for (int k = 0; k < 6; ++k) v[k] += __shfl_down(v[k], off, 64);
            if (lane == 0) {
                #pragma unroll
                for (int k = 0; k < 6; ++k) s_red[wid][k] = v[k];
            }
            __syncthreads();
            if (f == 0) {
                const float sxy  = s_red[0][0] + s_red[1][0];
                const float swh  = s_red[0][1] + s_red[1][1];
                const float scls = s_red[0][2] + s_red[1][2];
                const float spos = s_red[0][3] + s_red[1][3];
                const float scor = s_red[0][4] + s_red[1][4];
                const float nobj = s_red[0][5] + s_red[1][5];
                const float negs = s_nred[0][s] + s_nred[1][s];
                const float Ns = (s == 0) ? (float)(16 * 3 * 6400)
                               : (s == 1) ? (float)(16 * 3 * 1600)
                                          : (float)(16 * 3 * 400);
                const float n_noobj = Ns - nobj;
                const float lxywh = (sxy + swh) / fmaxf(2.f * nobj, 1.f);
                const float lcls  = scls / fmaxf(nobj * (float)NUM_CLASSES, 1.f);
                const float lpos  = spos / fmaxf(nobj, 1.f);
                const float lneg  = (negs + scor) / fmaxf(n_noobj, 1.f);
                const float has   = (nobj > 0.f) ? 1.f : 0.f;
                total += 5.f * lxywh * has + lpos * has + 0.5f * lneg + lcls * has;
            }
            __syncthreads();
        }
        if (f == 0) out[0] = total / 3.f;

        // reset flags for the next call (kernel completion drains these
        // before any subsequent dispatch can observe ws)
        __syncthreads();
        for (int i = f; i < OBJ_BLOCKS; i += 128)
            st_ws(ws + (size_t)i * 8 + 6, -1.0f);
        for (int q = f; q < NEG_BLOCKS; q += 128)
            st_ws(ws + NEG_BASE + q, -1.0f);
    }
}

extern "C" void kernel_launch(void* const* d_in, const int* in_sizes, int n_in,
                              void* d_out, int out_size, void* d_ws, size_t ws_size,
                              hipStream_t stream) {
    const float* p0  = (const float*)d_in[0];
    const float* p1  = (const float*)d_in[1];
    const float* p2  = (const float*)d_in[2];
    const float* tgt = (const float*)d_in[3];
    float* ws  = (float*)d_ws;   // uses 12486 floats ~= 49 KB
    float* out = (float*)d_out;

    fused_kernel<<<TOTAL_BLOCKS, 128, 0, stream>>>(p0, p1, p2, tgt, ws, out);
}